// Round 17
// baseline (836.092 us; speedup 1.0000x reference)
//
#include <hip/hip_runtime.h>
#include <hip/hip_fp16.h>
#include <math.h>

#define B_ 2
#define V_ 256
#define D_ 512
#define H_ 256
#define W_ 256
#define CH_ 96
#define PW 260                         // padded width/height (2px halo)

typedef _Float16 f16;
typedef f16 half8 __attribute__((ext_vector_type(8)));
typedef f16 half4 __attribute__((ext_vector_type(4)));
typedef f16 half2v __attribute__((ext_vector_type(2)));
typedef float f32x16 __attribute__((ext_vector_type(16)));

#if defined(__has_builtin)
#if __has_builtin(__builtin_amdgcn_fdot2)
#define FDOT2(a, b, c) __builtin_amdgcn_fdot2((a), (b), (c), false)
#endif
#endif
#ifndef FDOT2
#define FDOT2(a, b, c) ((c) + (float)(a)[0] * (float)(b)[0] + (float)(a)[1] * (float)(b)[1])
#endif

// Activation layout (f16): buf[batch][group=ci/16][PW*PW][16], zero border.
static const size_t PGSTR = (size_t)PW * PW * 16;   // f16 per plane

// ---------------------------------------------------------------------------
// 1) fused premultiply + Ram-Lak ramp filter. grid (V_, B_), block 256
__global__ void filter_kernel(const float* __restrict__ p,
                              const float* __restrict__ pw,
                              const float* __restrict__ ramp,
                              float* __restrict__ filt) {
  int v = blockIdx.x, b = blockIdx.y, t = threadIdx.x;
  __shared__ float s_pw[D_];
  __shared__ float s_ramp[2 * D_ - 1];
  const float* prow = p + (size_t)(b * V_ + v) * D_;
  const float* wrow = pw + (size_t)v * D_;
  s_pw[t] = prow[t] * wrow[t];
  s_pw[t + 256] = prow[t + 256] * wrow[t + 256];
  for (int i = t; i < 2 * D_ - 1; i += 256) s_ramp[i] = ramp[i];
  __syncthreads();
  float acc0 = 0.f, acc1 = 0.f;
  for (int m = 0; m < D_; ++m) {
    float x = s_pw[m];
    acc0 += x * s_ramp[m - t + (D_ - 1)];
    acc1 += x * s_ramp[m - (t + 256) + (D_ - 1)];
  }
  filt[(size_t)(b * V_ + v) * D_ + t] = acc0;
  filt[(size_t)(b * V_ + v) * D_ + t + 256] = acc1;
}

// ---------------------------------------------------------------------------
// 2) backprojection + wave-register PACKED-f16 bitonic sort (R15-verified).
// grid (HW/4, nb), block 256 (4 waves). xt[b][pix][v].
__global__ __launch_bounds__(256) void backproj_sort_kernel(
    const float* __restrict__ filt,
    const float* __restrict__ views,
    f16* __restrict__ xt) {
  __shared__ float s_c[V_], s_s[V_];
  int tid = threadIdx.x;
  int b = blockIdx.y;
  {
    float sn, cs;
    sincosf(views[tid], &sn, &cs);
    s_c[tid] = cs;
    s_s[tid] = sn;
  }
  __syncthreads();
  int lane = tid & 63;
  int wv = tid >> 6;
  int pix = blockIdx.x * 4 + wv;
  int h = pix >> 8, w = pix & 255;
  float X = (float)w - (W_ - 1) * 0.5f;
  float Y = (float)h - (H_ - 1) * 0.5f;
  const float* filt_b = filt + (size_t)b * V_ * D_;
  float r[4];
  #pragma unroll
  for (int i = 0; i < 4; ++i) {
    int v = lane * 4 + i;
    float u = X * s_c[v] + Y * s_s[v] + (D_ - 1) * 0.5f;
    float u0 = floorf(u);
    float frac = u - u0;
    int u0i = (int)u0;
    bool valid = (u0i >= 0) && (u0i <= D_ - 2);
    int u0c = min(max(u0i, 0), D_ - 2);
    const float* frow = filt_b + (size_t)v * D_;
    float g0 = frow[u0c], g1 = frow[u0c + 1];
    r[i] = valid ? (g0 * (1.f - frac) + g1 * frac) * (float)(M_PI / V_) : 0.f;
  }
  half2v A = { (f16)r[0], (f16)r[1] };
  half2v B = { (f16)r[2], (f16)r[3] };
  #pragma unroll
  for (int k = 2; k <= 256; k <<= 1) {
    #pragma unroll
    for (int j = k >> 1; j > 0; j >>= 1) {
      if (j >= 4) {
        int jl = j >> 2;
        bool low = (lane & jl) == 0;
        bool up = (lane & (k >> 2)) == 0;
        bool keepmin = (low == up);
        int ia = __builtin_bit_cast(int, A);
        int ib = __builtin_bit_cast(int, B);
        half2v Ao = __builtin_bit_cast(half2v, __shfl_xor(ia, jl, 64));
        half2v Bo = __builtin_bit_cast(half2v, __shfl_xor(ib, jl, 64));
        half2v Amn = __builtin_elementwise_min(A, Ao);
        half2v Amx = __builtin_elementwise_max(A, Ao);
        half2v Bmn = __builtin_elementwise_min(B, Bo);
        half2v Bmx = __builtin_elementwise_max(B, Bo);
        A = keepmin ? Amn : Amx;
        B = keepmin ? Bmn : Bmx;
      } else if (j == 2) {
        bool up = (lane & (k >> 2)) == 0;
        half2v mn = __builtin_elementwise_min(A, B);
        half2v mx = __builtin_elementwise_max(A, B);
        A = up ? mn : mx;
        B = up ? mx : mn;
      } else {  // j == 1
        unsigned ua = __builtin_bit_cast(unsigned, A);
        unsigned ub = __builtin_bit_cast(unsigned, B);
        half2v As = __builtin_bit_cast(half2v, (ua >> 16) | (ua << 16));
        half2v Bs = __builtin_bit_cast(half2v, (ub >> 16) | (ub << 16));
        unsigned amn = __builtin_bit_cast(unsigned, __builtin_elementwise_min(A, As));
        unsigned amx = __builtin_bit_cast(unsigned, __builtin_elementwise_max(A, As));
        unsigned bmn = __builtin_bit_cast(unsigned, __builtin_elementwise_min(B, Bs));
        unsigned bmx = __builtin_bit_cast(unsigned, __builtin_elementwise_max(B, Bs));
        unsigned Aasc  = (amn & 0xFFFFu) | (amx & 0xFFFF0000u);
        unsigned Adesc = (amx & 0xFFFFu) | (amn & 0xFFFF0000u);
        unsigned Basc  = (bmn & 0xFFFFu) | (bmx & 0xFFFF0000u);
        unsigned Bdesc = (bmx & 0xFFFFu) | (bmn & 0xFFFF0000u);
        bool upA, upB;
        if (k == 2) { upA = true; upB = false; }
        else { upA = upB = ((lane & (k >> 2)) == 0); }
        A = __builtin_bit_cast(half2v, upA ? Aasc : Adesc);
        B = __builtin_bit_cast(half2v, upB ? Basc : Bdesc);
      }
    }
  }
  half4 o;
  o[0] = A[0]; o[1] = A[1]; o[2] = B[0]; o[3] = B[1];
  *(half4*)(xt + ((size_t)b * (H_ * W_) + pix) * V_ + lane * 4) = o;
}

// ---------------------------------------------------------------------------
// 3) 3x3 conv, 256 sorted-view channels -> 1; fp32 out. grid (HW/4, nb)
__global__ __launch_bounds__(256) void conv_vred_kernel(
    const f16* __restrict__ xt,
    const float* __restrict__ cw,
    const float* __restrict__ cb,
    float* __restrict__ xin) {
  int tid = threadIdx.x;
  int b = blockIdx.y;
  int lane = tid & 63, wv = tid >> 6;
  int pix = blockIdx.x * 4 + wv;
  int h = pix >> 8, w = pix & 255;
  const f16* xtb = xt + (size_t)b * (H_ * W_) * V_;
  float wr[9][4];
  #pragma unroll
  for (int tap = 0; tap < 9; ++tap)
    #pragma unroll
    for (int i = 0; i < 4; ++i)
      wr[tap][i] = cw[(lane * 4 + i) * 9 + tap];
  float acc = 0.f;
  #pragma unroll
  for (int dy = -1; dy <= 1; ++dy) {
    int hh = h + dy;
    if (hh < 0 || hh >= H_) continue;
    #pragma unroll
    for (int dx = -1; dx <= 1; ++dx) {
      int ww = w + dx;
      if (ww < 0 || ww >= W_) continue;
      const f16* base = xtb + (((size_t)hh << 8) + ww) * V_ + lane * 4;
      half4 x4 = *(const half4*)base;
      int tap = (dy + 1) * 3 + dx + 1;
      acc += (float)x4[0] * wr[tap][0] + (float)x4[1] * wr[tap][1] +
             (float)x4[2] * wr[tap][2] + (float)x4[3] * wr[tap][3];
    }
  }
  for (int off = 32; off > 0; off >>= 1) acc += __shfl_down(acc, off);
  if (lane == 0) xin[(size_t)b * (H_ * W_) + pix] = acc + cb[0];
}

// ---------------------------------------------------------------------------
// 4) weight transpose+cast -> wT[layer][tap][cig][co][ci16] f16
__global__ void wtrans_kernel(const float* __restrict__ enc_w,
                              const float* __restrict__ dec_w,
                              f16* __restrict__ wT) {
  int idx = blockIdx.x * 256 + threadIdx.x;
  const int TOT = 8 * 25 * 96 * 96;
  if (idx >= TOT) return;
  int ci16 = idx & 15;
  int t1 = idx >> 4;
  int co = t1 % 96;
  int t2 = t1 / 96;
  int cig = t2 % 6;
  int t3 = t2 / 6;
  int tap = t3 % 25;
  int l = t3 / 25;
  int ci = cig * 16 + ci16;
  const float* src = (l < 4) ? (enc_w + (size_t)l * 96 * 96 * 25)
                             : (dec_w + (size_t)(l - 4) * 96 * 96 * 25);
  wT[idx] = (f16)src[((size_t)co * 96 + ci) * 25 + tap];
}

// ---------------------------------------------------------------------------
// 4b) zero the 2px borders of all padded activation planes (once per launch).
__global__ void zero_border_kernel(f16* __restrict__ base, int nplanes) {
  int idx = blockIdx.x * 256 + threadIdx.x;
  int total = nplanes * 2064;
  if (idx >= total) return;
  int p = idx / 2064, i = idx % 2064;
  int r, ccol;
  if (i < 520) { r = i / 260; ccol = i % 260; }
  else if (i < 1040) { int t = i - 520; r = 258 + t / 260; ccol = t % 260; }
  else { int t = i - 1040; r = 2 + (t >> 2); ccol = (t & 1) + ((t >> 1) & 1) * 258; }
  f16* pp = base + (size_t)p * PGSTR + ((size_t)r * PW + ccol) * 16;
  const uint4 z = {0u, 0u, 0u, 0u};
  *(uint4*)pp = z;
  *(uint4*)(pp + 8) = z;
}

// ---------------------------------------------------------------------------
// 5) MFMA implicit-GEMM 5x5 conv 96->96 — LDS-FREE. Padded group-planar
// activations make every B-fragment a contiguous, in-bounds global read
// (L1/L2-resident; per-wave window ~9 KB). Block = 256 thr = 4 independent
// waves (q = rows 4q..4q+3); blockIdx.y = co-group c. No barriers.
// grid (128, 3, nb), block 256.
__global__ __launch_bounds__(256, 4) void conv5_mfma_kernel(
    const f16* __restrict__ act,   // [nb][6][PW*PW][16] padded
    const f16* __restrict__ wTl,   // [25][6][96][16]
    const float* __restrict__ bias,
    const f16* __restrict__ res,   // nullable, padded layout
    f16* __restrict__ outp) {
  int tid = threadIdx.x;
  int lane = tid & 63;
  int l31 = lane & 31, lh = lane >> 5;
  int q = tid >> 6;             // 0..3
  int c = blockIdx.y;           // 0..2
  int bt = blockIdx.x;
  int x0 = (bt & 7) * 32;
  int y0 = (bt >> 3) * 16;
  size_t bofs = (size_t)blockIdx.z * (6 * PGSTR);
  const f16* actb = act + bofs;

  f32x16 acc[4];
  #pragma unroll
  for (int i = 0; i < 4; ++i)
    #pragma unroll
    for (int r = 0; r < 16; ++r) acc[i][r] = 0.f;

  const f16* wc = wTl + (size_t)(c * 32 + l31) * 16 + lh * 8;
  // padded B base: rows y0+4q+k (k=0..7), cols x0+l31+dx -> always in-bounds
  size_t rowbase = ((size_t)(y0 + 4 * q) * PW + x0 + l31) * 16 + lh * 8;

  for (int cig = 0; cig < 6; ++cig) {
    const f16* wcg = wc + (size_t)cig * (96 * 16);
    const f16* pb = actb + (size_t)cig * PGSTR + rowbase;
    #pragma unroll
    for (int dx = 0; dx < 5; ++dx) {
      half8 Bw[8];
      #pragma unroll
      for (int k = 0; k < 8; ++k)
        Bw[k] = *(const half8*)(pb + (size_t)(k * PW + dx) * 16);
      #pragma unroll
      for (int dy = 0; dy < 5; ++dy) {
        half8 Af = *(const half8*)(wcg + (size_t)(dy * 5 + dx) * (6 * 96 * 16));
        acc[0] = __builtin_amdgcn_mfma_f32_32x32x16_f16(Af, Bw[dy + 0], acc[0], 0, 0, 0);
        acc[1] = __builtin_amdgcn_mfma_f32_32x32x16_f16(Af, Bw[dy + 1], acc[1], 0, 0, 0);
        acc[2] = __builtin_amdgcn_mfma_f32_32x32x16_f16(Af, Bw[dy + 2], acc[2], 0, 0, 0);
        acc[3] = __builtin_amdgcn_mfma_f32_32x32x16_f16(Af, Bw[dy + 3], acc[3], 0, 0, 0);
      }
    }
  }

  // epilogue: ch = c*32+g*8+lh*4+r -> group c*2+(g>>1), off (g&1)*8+lh*4.
  int x = x0 + l31;
  #pragma unroll
  for (int i = 0; i < 4; ++i) {
    int y = y0 + 4 * q + i;
    size_t pp = ((size_t)(y + 2) * PW + (x + 2)) * 16;
    f32x16 a = acc[i];
    #pragma unroll
    for (int g = 0; g < 4; ++g) {
      int cg = c * 2 + (g >> 1);
      size_t ao = bofs + (size_t)cg * PGSTR + pp + (g & 1) * 8 + lh * 4;
      half4 rv;
      if (res) rv = *(const half4*)(res + ao);
      half4 o4;
      #pragma unroll
      for (int r = 0; r < 4; ++r) {
        float v = a[g * 4 + r] + bias[c * 32 + g * 8 + lh * 4 + r];
        if (res) v += (float)rv[r];
        o4[r] = (f16)fmaxf(v, 0.f);
      }
      *(half4*)(outp + ao) = o4;
    }
  }
}

// ---------------------------------------------------------------------------
// 6) first layer 1->96 direct, padded group-planar writes. grid (256, nb).
__global__ __launch_bounds__(256) void conv5_first_kernel(
    const float* __restrict__ xin, const float* __restrict__ w0,
    const float* __restrict__ bias, f16* __restrict__ A) {
  int tid = threadIdx.x;
  int tx = tid & 15, ty = tid >> 4;
  int x0 = (blockIdx.x & 15) * 16, y0 = (blockIdx.x >> 4) * 16;
  const float* xb = xin + (size_t)blockIdx.y * (H_ * W_);
  __shared__ float t[20][20];
  __shared__ float ws[CH_ * 25];
  for (int i = tid; i < 400; i += 256) {
    int r = i / 20, cc = i % 20;
    int gy = y0 + r - 2, gx = x0 + cc - 2;
    t[r][cc] = (gy >= 0 && gy < H_ && gx >= 0 && gx < W_) ? xb[gy * W_ + gx] : 0.f;
  }
  for (int i = tid; i < CH_ * 25; i += 256) ws[i] = w0[i];
  __syncthreads();
  float xv[25];
  #pragma unroll
  for (int k = 0; k < 25; ++k) xv[k] = t[ty + k / 5][tx + k % 5];
  size_t base = (size_t)blockIdx.y * (6 * PGSTR);
  size_t pp = ((size_t)(y0 + ty + 2) * PW + (x0 + tx + 2)) * 16;
  #pragma unroll
  for (int g = 0; g < 6; ++g) {
    f16 tmp[16];
    #pragma unroll
    for (int cc = 0; cc < 16; ++cc) {
      int ch = g * 16 + cc;
      float a0 = bias[ch];
      #pragma unroll
      for (int k = 0; k < 25; ++k) a0 = fmaf(xv[k], ws[ch * 25 + k], a0);
      tmp[cc] = (f16)fmaxf(a0, 0.f);
    }
    f16* Ap = A + base + (size_t)g * PGSTR + pp;
    *(uint4*)(Ap) = *(uint4*)(tmp);
    *(uint4*)(Ap + 8) = *(uint4*)(tmp + 8);
  }
}

// ---------------------------------------------------------------------------
// 7) last layer 96->1 + x_in residual, relu, fp32 out. Padded input, 6 LDS
// planes [400][16] XOR-swizzled, b128 reads, fdot2. grid (256, nb).
__global__ __launch_bounds__(256) void conv5_last_kernel(
    const f16* __restrict__ A, const float* __restrict__ wN,
    const float* __restrict__ bias, const float* __restrict__ xin,
    float* __restrict__ outp) {
  int tid = threadIdx.x;
  int tx = tid & 15, ty = tid >> 4;
  int x0 = (blockIdx.x & 15) * 16, y0 = (blockIdx.x >> 4) * 16;
  size_t bo = (size_t)blockIdx.y * (H_ * W_);
  const f16* Ab = A + (size_t)blockIdx.y * (6 * PGSTR);
  __shared__ __align__(16) f16 t[6 * 400 * 16];   // 76800 B
  __shared__ __align__(16) f16 wh[25 * CH_];      // 4800 B, [k][ch]
  char* tb = (char*)t;
  const int LPLANE = 400 * 32;                    // 12800 B
  for (int i = tid; i < 25 * CH_; i += 256) {
    int k = i / CH_, ci = i % CH_;
    wh[i] = (f16)wN[ci * 25 + k];
  }
  #pragma unroll
  for (int g = 0; g < 6; ++g) {
    const f16* Ag = Ab + (size_t)g * PGSTR;
    for (int idx = tid; idx < 800; idx += 256) {
      int cell = idx >> 1, j = idx & 1;
      int r = cell / 20, cc = cell % 20;
      // padded read: always in-bounds, border is zero
      uint4 v = *(const uint4*)(Ag + ((size_t)(y0 + r) * PW + (x0 + cc)) * 16 + j * 8);
      int sw = (cell & 7) << 4;
      *(uint4*)(tb + g * LPLANE + ((cell * 32 + j * 16) ^ sw)) = v;
    }
  }
  __syncthreads();
  float acc = bias[0];
  #pragma unroll
  for (int k = 0; k < 25; ++k) {
    int cellr = (ty + k / 5) * 20 + tx + k % 5;
    int sw = (cellr & 7) << 4;
    #pragma unroll
    for (int g = 0; g < 6; ++g) {
      const half2v* wp = (const half2v*)(wh + k * CH_ + g * 16);
      uint4 a0 = *(const uint4*)(tb + g * LPLANE + ((cellr * 32) ^ sw));
      uint4 a1 = *(const uint4*)(tb + g * LPLANE + ((cellr * 32 + 16) ^ sw));
      acc = FDOT2(__builtin_bit_cast(half2v, a0.x), wp[0], acc);
      acc = FDOT2(__builtin_bit_cast(half2v, a0.y), wp[1], acc);
      acc = FDOT2(__builtin_bit_cast(half2v, a0.z), wp[2], acc);
      acc = FDOT2(__builtin_bit_cast(half2v, a0.w), wp[3], acc);
      acc = FDOT2(__builtin_bit_cast(half2v, a1.x), wp[4], acc);
      acc = FDOT2(__builtin_bit_cast(half2v, a1.y), wp[5], acc);
      acc = FDOT2(__builtin_bit_cast(half2v, a1.z), wp[6], acc);
      acc = FDOT2(__builtin_bit_cast(half2v, a1.w), wp[7], acc);
    }
  }
  int pix = (y0 + ty) * W_ + x0 + tx;
  acc += xin[bo + pix];
  outp[bo + pix] = fmaxf(acc, 0.f);
}

// ---------------------------------------------------------------------------
__global__ void diag_kernel(float* __restrict__ out, int code, int wsMiB) {
  out[0] = (float)(code * 1000000 + wsMiB);
}

// ---------------------------------------------------------------------------
extern "C" void kernel_launch(void* const* d_in, const int* in_sizes, int n_in,
                              void* d_out, int out_size, void* d_ws, size_t ws_size,
                              hipStream_t stream) {
  const float* p       = (const float*)d_in[0];
  const float* pweight = (const float*)d_in[1];
  const float* ramp    = (const float*)d_in[2];
  const float* views   = (const float*)d_in[3];
  const float* conv_w  = (const float*)d_in[4];
  const float* conv_b  = (const float*)d_in[5];
  const float* enc_w0  = (const float*)d_in[6];
  const float* enc_w   = (const float*)d_in[7];
  const float* enc_b   = (const float*)d_in[8];
  const float* dec_w   = (const float*)d_in[9];
  const float* dec_wN  = (const float*)d_in[10];
  const float* dec_b   = (const float*)d_in[11];
  const float* dec_bN  = (const float*)d_in[12];
  float* out           = (float*)d_out;   // [2][256][256] fp32

  char* wsb   = (char*)d_ws;
  float* filt = (float*)(wsb);
  float* xin  = (float*)(wsb + 0x100000u);
  f16* wT     = (f16*)(wsb + 0x180000u);
  const size_t AOFF = 0x508000u;
  f16* xt     = (f16*)(wsb + AOFF);

  const size_t PACT = 6 * PGSTR;                      // f16 per padded batch
  const size_t NEEDED_SEQ  = AOFF + 3 * PACT * 2;     // ~42.2 MiB
  const size_t NEEDED_DUAL = AOFF + 6 * PACT * 2;     // ~79.5 MiB
  int wsMiB = (int)(ws_size >> 20);
  if (ws_size < NEEDED_SEQ) {
    diag_kernel<<<1, 1, 0, stream>>>(out, 9, wsMiB);
    return;
  }
  int nb = (ws_size >= NEEDED_DUAL) ? 2 : 1;
  size_t bufSz = (size_t)nb * PACT;
  f16* A  = (f16*)(wsb + AOFF);
  f16* Bb = A + bufSz;
  f16* C  = Bb + bufSz;

  const int HW = H_ * W_;
  const size_t WTL = 25 * 96 * 96;

  filter_kernel<<<dim3(V_, B_), 256, 0, stream>>>(p, pweight, ramp, filt);
  wtrans_kernel<<<7200, 256, 0, stream>>>(enc_w, dec_w, wT);

  if (nb == 2) {
    backproj_sort_kernel<<<dim3(HW / 4, 2), 256, 0, stream>>>(filt, views, xt);
    conv_vred_kernel<<<dim3(HW / 4, 2), 256, 0, stream>>>(xt, conv_w, conv_b, xin);
  } else {
    for (int b = 0; b < B_; ++b) {
      backproj_sort_kernel<<<dim3(HW / 4, 1), 256, 0, stream>>>(filt + (size_t)b * V_ * D_, views, xt);
      conv_vred_kernel<<<dim3(HW / 4, 1), 256, 0, stream>>>(xt, conv_w, conv_b, xin + (size_t)b * HW);
    }
  }
  // xt is dead; zero borders of all padded activation buffers (A,Bb,C).
  {
    int nplanes = 3 * nb * 6;
    int total = nplanes * 2064;
    zero_border_kernel<<<(total + 255) / 256, 256, 0, stream>>>(A, nplanes);
  }

  auto run_net = [&](const float* xin_g, float* out_g, int nbat) {
    dim3 gL(128, 3, nbat);
    dim3 gS(256, nbat);
    conv5_first_kernel<<<gS, 256, 0, stream>>>(xin_g, enc_w0, enc_b, A);
    conv5_mfma_kernel<<<gL, 256, 0, stream>>>(A,  wT + 0 * WTL, enc_b + 96,  nullptr, Bb); // h2 (r2)
    conv5_mfma_kernel<<<gL, 256, 0, stream>>>(Bb, wT + 1 * WTL, enc_b + 192, nullptr, A);  // h3
    conv5_mfma_kernel<<<gL, 256, 0, stream>>>(A,  wT + 2 * WTL, enc_b + 288, nullptr, C);  // h4 (r3)
    conv5_mfma_kernel<<<gL, 256, 0, stream>>>(C,  wT + 3 * WTL, enc_b + 384, nullptr, A);  // h5
    conv5_mfma_kernel<<<gL, 256, 0, stream>>>(A,  wT + 4 * WTL, dec_b + 0,   C,       C);  // h6 (+r3)
    conv5_mfma_kernel<<<gL, 256, 0, stream>>>(C,  wT + 5 * WTL, dec_b + 96,  nullptr, A);  // h7
    conv5_mfma_kernel<<<gL, 256, 0, stream>>>(A,  wT + 6 * WTL, dec_b + 192, Bb,      Bb); // h8 (+r2)
    conv5_mfma_kernel<<<gL, 256, 0, stream>>>(Bb, wT + 7 * WTL, dec_b + 288, nullptr, A);  // h9
    conv5_last_kernel<<<gS, 256, 0, stream>>>(A, dec_wN, dec_bN, xin_g, out_g);
  };

  if (nb == 2) {
    run_net(xin, out, 2);
  } else {
    for (int b = 0; b < B_; ++b)
      run_net(xin + (size_t)b * HW, out + (size_t)b * HW, 1);
  }
}

// Round 18
// 662.731 us; speedup vs baseline: 1.2616x; 1.2616x over previous
//
#include <hip/hip_runtime.h>
#include <hip/hip_fp16.h>
#include <math.h>

#define B_ 2
#define V_ 256
#define D_ 512
#define H_ 256
#define W_ 256
#define CH_ 96

typedef _Float16 f16;
typedef f16 half8 __attribute__((ext_vector_type(8)));
typedef f16 half4 __attribute__((ext_vector_type(4)));
typedef f16 half2v __attribute__((ext_vector_type(2)));
typedef float f32x16 __attribute__((ext_vector_type(16)));

#if defined(__has_builtin)
#if __has_builtin(__builtin_amdgcn_fdot2)
#define FDOT2(a, b, c) __builtin_amdgcn_fdot2((a), (b), (c), false)
#endif
#endif
#ifndef FDOT2
#define FDOT2(a, b, c) ((c) + (float)(a)[0] * (float)(b)[0] + (float)(a)[1] * (float)(b)[1])
#endif

// Activation layout (f16): buf[batch][group=ci/16][H*W][16]  -- group-planar.

// ---------------------------------------------------------------------------
// 1) fused premultiply + Ram-Lak ramp filter. grid (V_, B_), block 256
__global__ void filter_kernel(const float* __restrict__ p,
                              const float* __restrict__ pw,
                              const float* __restrict__ ramp,
                              float* __restrict__ filt) {
  int v = blockIdx.x, b = blockIdx.y, t = threadIdx.x;
  __shared__ float s_pw[D_];
  __shared__ float s_ramp[2 * D_ - 1];
  const float* prow = p + (size_t)(b * V_ + v) * D_;
  const float* wrow = pw + (size_t)v * D_;
  s_pw[t] = prow[t] * wrow[t];
  s_pw[t + 256] = prow[t + 256] * wrow[t + 256];
  for (int i = t; i < 2 * D_ - 1; i += 256) s_ramp[i] = ramp[i];
  __syncthreads();
  float acc0 = 0.f, acc1 = 0.f;
  for (int m = 0; m < D_; ++m) {
    float x = s_pw[m];
    acc0 += x * s_ramp[m - t + (D_ - 1)];
    acc1 += x * s_ramp[m - (t + 256) + (D_ - 1)];
  }
  filt[(size_t)(b * V_ + v) * D_ + t] = acc0;
  filt[(size_t)(b * V_ + v) * D_ + t + 256] = acc1;
}

// ---------------------------------------------------------------------------
// 2) backprojection + wave-register PACKED-f16 bitonic sort.
// grid (HW/4, nb), block 256 (4 waves). xt[b][pix][v].
__global__ __launch_bounds__(256) void backproj_sort_kernel(
    const float* __restrict__ filt,
    const float* __restrict__ views,
    f16* __restrict__ xt) {
  __shared__ float s_c[V_], s_s[V_];
  int tid = threadIdx.x;
  int b = blockIdx.y;
  {
    float sn, cs;
    sincosf(views[tid], &sn, &cs);
    s_c[tid] = cs;
    s_s[tid] = sn;
  }
  __syncthreads();
  int lane = tid & 63;
  int wv = tid >> 6;
  int pix = blockIdx.x * 4 + wv;
  int h = pix >> 8, w = pix & 255;
  float X = (float)w - (W_ - 1) * 0.5f;
  float Y = (float)h - (H_ - 1) * 0.5f;
  const float* filt_b = filt + (size_t)b * V_ * D_;
  float r[4];
  #pragma unroll
  for (int i = 0; i < 4; ++i) {
    int v = lane * 4 + i;
    float u = X * s_c[v] + Y * s_s[v] + (D_ - 1) * 0.5f;
    float u0 = floorf(u);
    float frac = u - u0;
    int u0i = (int)u0;
    bool valid = (u0i >= 0) && (u0i <= D_ - 2);
    int u0c = min(max(u0i, 0), D_ - 2);
    const float* frow = filt_b + (size_t)v * D_;
    float g0 = frow[u0c], g1 = frow[u0c + 1];
    r[i] = valid ? (g0 * (1.f - frac) + g1 * frac) * (float)(M_PI / V_) : 0.f;
  }
  half2v A = { (f16)r[0], (f16)r[1] };
  half2v B = { (f16)r[2], (f16)r[3] };
  #pragma unroll
  for (int k = 2; k <= 256; k <<= 1) {
    #pragma unroll
    for (int j = k >> 1; j > 0; j >>= 1) {
      if (j >= 4) {
        int jl = j >> 2;
        bool low = (lane & jl) == 0;
        bool up = (lane & (k >> 2)) == 0;
        bool keepmin = (low == up);
        int ia = __builtin_bit_cast(int, A);
        int ib = __builtin_bit_cast(int, B);
        half2v Ao = __builtin_bit_cast(half2v, __shfl_xor(ia, jl, 64));
        half2v Bo = __builtin_bit_cast(half2v, __shfl_xor(ib, jl, 64));
        half2v Amn = __builtin_elementwise_min(A, Ao);
        half2v Amx = __builtin_elementwise_max(A, Ao);
        half2v Bmn = __builtin_elementwise_min(B, Bo);
        half2v Bmx = __builtin_elementwise_max(B, Bo);
        A = keepmin ? Amn : Amx;
        B = keepmin ? Bmn : Bmx;
      } else if (j == 2) {
        bool up = (lane & (k >> 2)) == 0;
        half2v mn = __builtin_elementwise_min(A, B);
        half2v mx = __builtin_elementwise_max(A, B);
        A = up ? mn : mx;
        B = up ? mx : mn;
      } else {  // j == 1
        unsigned ua = __builtin_bit_cast(unsigned, A);
        unsigned ub = __builtin_bit_cast(unsigned, B);
        half2v As = __builtin_bit_cast(half2v, (ua >> 16) | (ua << 16));
        half2v Bs = __builtin_bit_cast(half2v, (ub >> 16) | (ub << 16));
        unsigned amn = __builtin_bit_cast(unsigned, __builtin_elementwise_min(A, As));
        unsigned amx = __builtin_bit_cast(unsigned, __builtin_elementwise_max(A, As));
        unsigned bmn = __builtin_bit_cast(unsigned, __builtin_elementwise_min(B, Bs));
        unsigned bmx = __builtin_bit_cast(unsigned, __builtin_elementwise_max(B, Bs));
        unsigned Aasc  = (amn & 0xFFFFu) | (amx & 0xFFFF0000u);
        unsigned Adesc = (amx & 0xFFFFu) | (amn & 0xFFFF0000u);
        unsigned Basc  = (bmn & 0xFFFFu) | (bmx & 0xFFFF0000u);
        unsigned Bdesc = (bmx & 0xFFFFu) | (bmn & 0xFFFF0000u);
        bool upA, upB;
        if (k == 2) { upA = true; upB = false; }
        else { upA = upB = ((lane & (k >> 2)) == 0); }
        A = __builtin_bit_cast(half2v, upA ? Aasc : Adesc);
        B = __builtin_bit_cast(half2v, upB ? Basc : Bdesc);
      }
    }
  }
  half4 o;
  o[0] = A[0]; o[1] = A[1]; o[2] = B[0]; o[3] = B[1];
  *(half4*)(xt + ((size_t)b * (H_ * W_) + pix) * V_ + lane * 4) = o;
}

// ---------------------------------------------------------------------------
// 3) 3x3 conv, 256 sorted-view channels -> 1; fp32 out. grid (HW/4, nb)
__global__ __launch_bounds__(256) void conv_vred_kernel(
    const f16* __restrict__ xt,
    const float* __restrict__ cw,
    const float* __restrict__ cb,
    float* __restrict__ xin) {
  int tid = threadIdx.x;
  int b = blockIdx.y;
  int lane = tid & 63, wv = tid >> 6;
  int pix = blockIdx.x * 4 + wv;
  int h = pix >> 8, w = pix & 255;
  const f16* xtb = xt + (size_t)b * (H_ * W_) * V_;
  float wr[9][4];
  #pragma unroll
  for (int tap = 0; tap < 9; ++tap)
    #pragma unroll
    for (int i = 0; i < 4; ++i)
      wr[tap][i] = cw[(lane * 4 + i) * 9 + tap];
  float acc = 0.f;
  #pragma unroll
  for (int dy = -1; dy <= 1; ++dy) {
    int hh = h + dy;
    if (hh < 0 || hh >= H_) continue;
    #pragma unroll
    for (int dx = -1; dx <= 1; ++dx) {
      int ww = w + dx;
      if (ww < 0 || ww >= W_) continue;
      const f16* base = xtb + (((size_t)hh << 8) + ww) * V_ + lane * 4;
      half4 x4 = *(const half4*)base;
      int tap = (dy + 1) * 3 + dx + 1;
      acc += (float)x4[0] * wr[tap][0] + (float)x4[1] * wr[tap][1] +
             (float)x4[2] * wr[tap][2] + (float)x4[3] * wr[tap][3];
    }
  }
  for (int off = 32; off > 0; off >>= 1) acc += __shfl_down(acc, off);
  if (lane == 0) xin[(size_t)b * (H_ * W_) + pix] = acc + cb[0];
}

// ---------------------------------------------------------------------------
// 4) weight transpose+cast -> wT[layer][tap][cig][co][ci16] f16
__global__ void wtrans_kernel(const float* __restrict__ enc_w,
                              const float* __restrict__ dec_w,
                              f16* __restrict__ wT) {
  int idx = blockIdx.x * 256 + threadIdx.x;
  const int TOT = 8 * 25 * 96 * 96;
  if (idx >= TOT) return;
  int ci16 = idx & 15;
  int t1 = idx >> 4;
  int co = t1 % 96;
  int t2 = t1 / 96;
  int cig = t2 % 6;
  int t3 = t2 / 6;
  int tap = t3 % 25;
  int l = t3 / 25;
  int ci = cig * 16 + ci16;
  const float* src = (l < 4) ? (enc_w + (size_t)l * 96 * 96 * 25)
                             : (dec_w + (size_t)(l - 4) * 96 * 96 * 25);
  wT[idx] = (f16)src[((size_t)co * 96 + ci) * 25 + tap];
}

// ---------------------------------------------------------------------------
// 5) MFMA implicit-GEMM 5x5 conv 96->96, barrier-free, B-window row reuse.
// R15 structure; LDS is LINEAR (no swizzle): staging writes are idx*16
// contiguous per instruction, B-reads per (dx,k) are a contiguous 1KB
// window (2 lanes/bank = free). grid (128, 1, nb), block 768.
__global__ __launch_bounds__(768, 3) void conv5_mfma_kernel(
    const f16* __restrict__ act,   // [nb][6][H*W][16]
    const f16* __restrict__ wTl,   // [25][6][96][16]
    const float* __restrict__ bias,
    const f16* __restrict__ res,   // nullable, same layout as act
    f16* __restrict__ outp) {
  int tid = threadIdx.x;
  int lane = tid & 63;
  int l31 = lane & 31, lh = lane >> 5;
  int wvi = tid >> 6;       // 0..11
  int c = wvi >> 2;         // co-group 0..2
  int q = wvi & 3;          // row quad 0..3
  int bt = blockIdx.x;
  int x0 = (bt & 7) * 32;
  int y0 = (bt >> 3) * 16;
  size_t bofs = (size_t)blockIdx.z * ((size_t)H_ * W_ * CH_);
  const f16* actb = act + bofs;

  __shared__ __align__(16) f16 tile[6 * 20 * 36 * 16];
  char* tb = (char*)tile;
  const int PLANE = 20 * 36 * 32;   // 23040 B
  const int ROWB  = 36 * 32;        // 1152 B
  const size_t GSTR = (size_t)H_ * W_ * 16;  // group stride (f16)

  // ---- stage whole 96-ci tile once; linear LDS, contiguous writes ----
  #pragma unroll
  for (int g = 0; g < 6; ++g) {
    const f16* gb = actb + (size_t)g * GSTR;
    #pragma unroll
    for (int pass = 0; pass < 2; ++pass) {
      int idx = pass * 768 + tid;          // 1440 slots = 720 cells x 2
      int cell = idx >> 1, j = idx & 1;
      if (cell < 720) {
        int row = cell / 36, xx = cell % 36;
        int gy = y0 + row - 2, gx = x0 + xx - 2;
        bool va = (gy >= 0 && gy < H_ && gx >= 0 && gx < W_);
        uint4 v = {0u, 0u, 0u, 0u};
        if (va) v = *(const uint4*)(gb + ((size_t)(gy * W_ + gx)) * 16 + j * 8);
        *(uint4*)(tb + g * PLANE + idx * 16) = v;
      }
    }
  }
  __syncthreads();

  // ds_read base per dx (linear; plane/row added as constants)
  int dsb[5];
  #pragma unroll
  for (int dx = 0; dx < 5; ++dx)
    dsb[dx] = (l31 + dx) * 32 + lh * 16;

  f32x16 acc[4];
  #pragma unroll
  for (int i = 0; i < 4; ++i)
    #pragma unroll
    for (int r = 0; r < 16; ++r) acc[i][r] = 0.f;

  const f16* wc = wTl + (size_t)(c * 32 + l31) * 16 + lh * 8;

  for (int cig = 0; cig < 6; ++cig) {
    const f16* wcg = wc + (size_t)cig * (96 * 16);
    char* pb = tb + cig * PLANE + 4 * q * ROWB;
    #pragma unroll
    for (int dx = 0; dx < 5; ++dx) {
      half8 Af[5];
      #pragma unroll
      for (int dy = 0; dy < 5; ++dy)
        Af[dy] = *(const half8*)(wcg + (size_t)(dy * 5 + dx) * (6 * 96 * 16));
      half8 Bw[8];
      #pragma unroll
      for (int k = 0; k < 8; ++k)
        Bw[k] = *(const half8*)(pb + k * ROWB + dsb[dx]);
      #pragma unroll
      for (int dy = 0; dy < 5; ++dy) {
        acc[0] = __builtin_amdgcn_mfma_f32_32x32x16_f16(Af[dy], Bw[dy + 0], acc[0], 0, 0, 0);
        acc[1] = __builtin_amdgcn_mfma_f32_32x32x16_f16(Af[dy], Bw[dy + 1], acc[1], 0, 0, 0);
        acc[2] = __builtin_amdgcn_mfma_f32_32x32x16_f16(Af[dy], Bw[dy + 2], acc[2], 0, 0, 0);
        acc[3] = __builtin_amdgcn_mfma_f32_32x32x16_f16(Af[dy], Bw[dy + 3], acc[3], 0, 0, 0);
      }
    }
  }

  // epilogue: C col = pixel x (lane&31), row co = (reg&3)+8*(reg>>2)+4*lh.
  // Group-planar output: ch = c*32+g*8+lh*4+r -> group c*2+(g>>1), off (g&1)*8+lh*4.
  int x = x0 + l31;
  #pragma unroll
  for (int i = 0; i < 4; ++i) {
    int y = y0 + 4 * q + i;
    int p = y * W_ + x;
    f32x16 a = acc[i];
    #pragma unroll
    for (int g = 0; g < 4; ++g) {
      int cg = c * 2 + (g >> 1);
      size_t ao = bofs + (size_t)cg * GSTR + (size_t)p * 16 + (g & 1) * 8 + lh * 4;
      half4 rv;
      if (res) rv = *(const half4*)(res + ao);
      half4 o4;
      #pragma unroll
      for (int r = 0; r < 4; ++r) {
        float v = a[g * 4 + r] + bias[c * 32 + g * 8 + lh * 4 + r];
        if (res) v += (float)rv[r];
        o4[r] = (f16)fmaxf(v, 0.f);
      }
      *(half4*)(outp + ao) = o4;
    }
  }
}

// ---------------------------------------------------------------------------
// 6) first layer 1->96 direct, group-planar writes. grid (256, nb).
__global__ __launch_bounds__(256) void conv5_first_kernel(
    const float* __restrict__ xin, const float* __restrict__ w0,
    const float* __restrict__ bias, f16* __restrict__ A) {
  int tid = threadIdx.x;
  int tx = tid & 15, ty = tid >> 4;
  int x0 = (blockIdx.x & 15) * 16, y0 = (blockIdx.x >> 4) * 16;
  const float* xb = xin + (size_t)blockIdx.y * (H_ * W_);
  __shared__ float t[20][20];
  __shared__ float ws[CH_ * 25];
  for (int i = tid; i < 400; i += 256) {
    int r = i / 20, cc = i % 20;
    int gy = y0 + r - 2, gx = x0 + cc - 2;
    t[r][cc] = (gy >= 0 && gy < H_ && gx >= 0 && gx < W_) ? xb[gy * W_ + gx] : 0.f;
  }
  for (int i = tid; i < CH_ * 25; i += 256) ws[i] = w0[i];
  __syncthreads();
  float xv[25];
  #pragma unroll
  for (int k = 0; k < 25; ++k) xv[k] = t[ty + k / 5][tx + k % 5];
  size_t base = (size_t)blockIdx.y * ((size_t)H_ * W_ * CH_);
  const size_t GSTR = (size_t)H_ * W_ * 16;
  int p = (y0 + ty) * W_ + x0 + tx;
  #pragma unroll
  for (int g = 0; g < 6; ++g) {
    f16 tmp[16];
    #pragma unroll
    for (int cc = 0; cc < 16; ++cc) {
      int ch = g * 16 + cc;
      float a0 = bias[ch];
      #pragma unroll
      for (int k = 0; k < 25; ++k) a0 = fmaf(xv[k], ws[ch * 25 + k], a0);
      tmp[cc] = (f16)fmaxf(a0, 0.f);
    }
    f16* Ap = A + base + g * GSTR + (size_t)p * 16;
    *(uint4*)(Ap) = *(uint4*)(tmp);
    *(uint4*)(Ap + 8) = *(uint4*)(tmp + 8);
  }
}

// ---------------------------------------------------------------------------
// 7) last layer 96->1 + x_in residual, relu, fp32 out. Group-planar input,
// 6 LDS planes [400][16] XOR-swizzled (different access pattern -> keep),
// b128 reads, fdot2. grid (256, nb).
__global__ __launch_bounds__(256) void conv5_last_kernel(
    const f16* __restrict__ A, const float* __restrict__ wN,
    const float* __restrict__ bias, const float* __restrict__ xin,
    float* __restrict__ outp) {
  int tid = threadIdx.x;
  int tx = tid & 15, ty = tid >> 4;
  int x0 = (blockIdx.x & 15) * 16, y0 = (blockIdx.x >> 4) * 16;
  size_t bo = (size_t)blockIdx.y * (H_ * W_);
  const f16* Ab = A + bo * CH_;
  const size_t GSTR = (size_t)H_ * W_ * 16;
  __shared__ __align__(16) f16 t[6 * 400 * 16];   // 76800 B
  __shared__ __align__(16) f16 wh[25 * CH_];      // 4800 B, [k][ch]
  char* tb = (char*)t;
  const int LPLANE = 400 * 32;                    // 12800 B
  for (int i = tid; i < 25 * CH_; i += 256) {
    int k = i / CH_, ci = i % CH_;
    wh[i] = (f16)wN[ci * 25 + k];
  }
  #pragma unroll
  for (int g = 0; g < 6; ++g) {
    const f16* Ag = Ab + (size_t)g * GSTR;
    for (int idx = tid; idx < 800; idx += 256) {
      int cell = idx >> 1, j = idx & 1;
      int r = cell / 20, cc = cell % 20;
      int gy = y0 + r - 2, gx = x0 + cc - 2;
      bool va = (gy >= 0 && gy < H_ && gx >= 0 && gx < W_);
      uint4 v = {0u, 0u, 0u, 0u};
      if (va) v = *(const uint4*)(Ag + ((size_t)(gy * W_ + gx)) * 16 + j * 8);
      int sw = (cell & 7) << 4;
      *(uint4*)(tb + g * LPLANE + ((cell * 32 + j * 16) ^ sw)) = v;
    }
  }
  __syncthreads();
  float acc = bias[0];
  #pragma unroll
  for (int k = 0; k < 25; ++k) {
    int cellr = (ty + k / 5) * 20 + tx + k % 5;
    int sw = (cellr & 7) << 4;
    #pragma unroll
    for (int g = 0; g < 6; ++g) {
      const half2v* wp = (const half2v*)(wh + k * CH_ + g * 16);
      uint4 a0 = *(const uint4*)(tb + g * LPLANE + ((cellr * 32) ^ sw));
      uint4 a1 = *(const uint4*)(tb + g * LPLANE + ((cellr * 32 + 16) ^ sw));
      acc = FDOT2(__builtin_bit_cast(half2v, a0.x), wp[0], acc);
      acc = FDOT2(__builtin_bit_cast(half2v, a0.y), wp[1], acc);
      acc = FDOT2(__builtin_bit_cast(half2v, a0.z), wp[2], acc);
      acc = FDOT2(__builtin_bit_cast(half2v, a0.w), wp[3], acc);
      acc = FDOT2(__builtin_bit_cast(half2v, a1.x), wp[4], acc);
      acc = FDOT2(__builtin_bit_cast(half2v, a1.y), wp[5], acc);
      acc = FDOT2(__builtin_bit_cast(half2v, a1.z), wp[6], acc);
      acc = FDOT2(__builtin_bit_cast(half2v, a1.w), wp[7], acc);
    }
  }
  int pix = (y0 + ty) * W_ + x0 + tx;
  acc += xin[bo + pix];
  outp[bo + pix] = fmaxf(acc, 0.f);
}

// ---------------------------------------------------------------------------
__global__ void diag_kernel(float* __restrict__ out, int code, int wsMiB) {
  out[0] = (float)(code * 1000000 + wsMiB);
}

// ---------------------------------------------------------------------------
extern "C" void kernel_launch(void* const* d_in, const int* in_sizes, int n_in,
                              void* d_out, int out_size, void* d_ws, size_t ws_size,
                              hipStream_t stream) {
  const float* p       = (const float*)d_in[0];
  const float* pweight = (const float*)d_in[1];
  const float* ramp    = (const float*)d_in[2];
  const float* views   = (const float*)d_in[3];
  const float* conv_w  = (const float*)d_in[4];
  const float* conv_b  = (const float*)d_in[5];
  const float* enc_w0  = (const float*)d_in[6];
  const float* enc_w   = (const float*)d_in[7];
  const float* enc_b   = (const float*)d_in[8];
  const float* dec_w   = (const float*)d_in[9];
  const float* dec_wN  = (const float*)d_in[10];
  const float* dec_b   = (const float*)d_in[11];
  const float* dec_bN  = (const float*)d_in[12];
  float* out           = (float*)d_out;   // [2][256][256] fp32

  char* wsb   = (char*)d_ws;
  float* filt = (float*)(wsb);
  float* xin  = (float*)(wsb + 0x100000u);
  f16* wT     = (f16*)(wsb + 0x180000u);
  const size_t AOFF = 0x508000u;
  f16* xt     = (f16*)(wsb + AOFF);

  const size_t ACT = (size_t)H_ * W_ * CH_;
  const size_t NEEDED_SEQ  = AOFF + 3 * ACT * 2;
  const size_t NEEDED_DUAL = AOFF + 6 * ACT * 2;
  int wsMiB = (int)(ws_size >> 20);
  if (ws_size < NEEDED_SEQ) {
    diag_kernel<<<1, 1, 0, stream>>>(out, 9, wsMiB);
    return;
  }
  int nb = (ws_size >= NEEDED_DUAL) ? 2 : 1;
  size_t bufSz = (size_t)nb * ACT;
  f16* A  = (f16*)(wsb + AOFF);
  f16* Bb = A + bufSz;
  f16* C  = Bb + bufSz;

  const int HW = H_ * W_;
  const size_t WTL = 25 * 96 * 96;

  filter_kernel<<<dim3(V_, B_), 256, 0, stream>>>(p, pweight, ramp, filt);
  wtrans_kernel<<<7200, 256, 0, stream>>>(enc_w, dec_w, wT);

  if (nb == 2) {
    backproj_sort_kernel<<<dim3(HW / 4, 2), 256, 0, stream>>>(filt, views, xt);
    conv_vred_kernel<<<dim3(HW / 4, 2), 256, 0, stream>>>(xt, conv_w, conv_b, xin);
  } else {
    for (int b = 0; b < B_; ++b) {
      backproj_sort_kernel<<<dim3(HW / 4, 1), 256, 0, stream>>>(filt + (size_t)b * V_ * D_, views, xt);
      conv_vred_kernel<<<dim3(HW / 4, 1), 256, 0, stream>>>(xt, conv_w, conv_b, xin + (size_t)b * HW);
    }
  }

  auto run_net = [&](const float* xin_g, float* out_g, int nbat) {
    dim3 gL(128, 1, nbat);
    dim3 gS(256, nbat);
    conv5_first_kernel<<<gS, 256, 0, stream>>>(xin_g, enc_w0, enc_b, A);
    conv5_mfma_kernel<<<gL, 768, 0, stream>>>(A,  wT + 0 * WTL, enc_b + 96,  nullptr, Bb); // h2 (r2)
    conv5_mfma_kernel<<<gL, 768, 0, stream>>>(Bb, wT + 1 * WTL, enc_b + 192, nullptr, A);  // h3
    conv5_mfma_kernel<<<gL, 768, 0, stream>>>(A,  wT + 2 * WTL, enc_b + 288, nullptr, C);  // h4 (r3)
    conv5_mfma_kernel<<<gL, 768, 0, stream>>>(C,  wT + 3 * WTL, enc_b + 384, nullptr, A);  // h5
    conv5_mfma_kernel<<<gL, 768, 0, stream>>>(A,  wT + 4 * WTL, dec_b + 0,   C,       C);  // h6 (+r3)
    conv5_mfma_kernel<<<gL, 768, 0, stream>>>(C,  wT + 5 * WTL, dec_b + 96,  nullptr, A);  // h7
    conv5_mfma_kernel<<<gL, 768, 0, stream>>>(A,  wT + 6 * WTL, dec_b + 192, Bb,      Bb); // h8 (+r2)
    conv5_mfma_kernel<<<gL, 768, 0, stream>>>(Bb, wT + 7 * WTL, dec_b + 288, nullptr, A);  // h9
    conv5_last_kernel<<<gS, 256, 0, stream>>>(A, dec_wN, dec_bN, xin_g, out_g);
  };

  if (nb == 2) {
    run_net(xin, out, 2);
  } else {
    for (int b = 0; b < B_; ++b)
      run_net(xin + (size_t)b * HW, out + (size_t)b * HW, 1);
  }
}

// Round 19
// 660.843 us; speedup vs baseline: 1.2652x; 1.0029x over previous
//
#include <hip/hip_runtime.h>
#include <hip/hip_fp16.h>
#include <math.h>

#define B_ 2
#define V_ 256
#define D_ 512
#define H_ 256
#define W_ 256
#define CH_ 96

typedef _Float16 f16;
typedef f16 half8 __attribute__((ext_vector_type(8)));
typedef f16 half4 __attribute__((ext_vector_type(4)));
typedef f16 half2v __attribute__((ext_vector_type(2)));
typedef float f32x16 __attribute__((ext_vector_type(16)));

#if defined(__has_builtin)
#if __has_builtin(__builtin_amdgcn_fdot2)
#define FDOT2(a, b, c) __builtin_amdgcn_fdot2((a), (b), (c), false)
#endif
#endif
#ifndef FDOT2
#define FDOT2(a, b, c) ((c) + (float)(a)[0] * (float)(b)[0] + (float)(a)[1] * (float)(b)[1])
#endif

// Activation layout (f16): buf[batch][group=ci/16][H*W][16]  -- group-planar.

// ---------------------------------------------------------------------------
// 1) fused premultiply + Ram-Lak ramp filter. grid (V_, B_), block 256
__global__ void filter_kernel(const float* __restrict__ p,
                              const float* __restrict__ pw,
                              const float* __restrict__ ramp,
                              float* __restrict__ filt) {
  int v = blockIdx.x, b = blockIdx.y, t = threadIdx.x;
  __shared__ float s_pw[D_];
  __shared__ float s_ramp[2 * D_ - 1];
  const float* prow = p + (size_t)(b * V_ + v) * D_;
  const float* wrow = pw + (size_t)v * D_;
  s_pw[t] = prow[t] * wrow[t];
  s_pw[t + 256] = prow[t + 256] * wrow[t + 256];
  for (int i = t; i < 2 * D_ - 1; i += 256) s_ramp[i] = ramp[i];
  __syncthreads();
  float acc0 = 0.f, acc1 = 0.f;
  for (int m = 0; m < D_; ++m) {
    float x = s_pw[m];
    acc0 += x * s_ramp[m - t + (D_ - 1)];
    acc1 += x * s_ramp[m - (t + 256) + (D_ - 1)];
  }
  filt[(size_t)(b * V_ + v) * D_ + t] = acc0;
  filt[(size_t)(b * V_ + v) * D_ + t + 256] = acc1;
}

// ---------------------------------------------------------------------------
// 2) backprojection + wave-register PACKED-f16 bitonic sort.
// grid (HW/4, nb), block 256 (4 waves). xt[b][pix][v].
__global__ __launch_bounds__(256) void backproj_sort_kernel(
    const float* __restrict__ filt,
    const float* __restrict__ views,
    f16* __restrict__ xt) {
  __shared__ float s_c[V_], s_s[V_];
  int tid = threadIdx.x;
  int b = blockIdx.y;
  {
    float sn, cs;
    sincosf(views[tid], &sn, &cs);
    s_c[tid] = cs;
    s_s[tid] = sn;
  }
  __syncthreads();
  int lane = tid & 63;
  int wv = tid >> 6;
  int pix = blockIdx.x * 4 + wv;
  int h = pix >> 8, w = pix & 255;
  float X = (float)w - (W_ - 1) * 0.5f;
  float Y = (float)h - (H_ - 1) * 0.5f;
  const float* filt_b = filt + (size_t)b * V_ * D_;
  float r[4];
  #pragma unroll
  for (int i = 0; i < 4; ++i) {
    int v = lane * 4 + i;
    float u = X * s_c[v] + Y * s_s[v] + (D_ - 1) * 0.5f;
    float u0 = floorf(u);
    float frac = u - u0;
    int u0i = (int)u0;
    bool valid = (u0i >= 0) && (u0i <= D_ - 2);
    int u0c = min(max(u0i, 0), D_ - 2);
    const float* frow = filt_b + (size_t)v * D_;
    float g0 = frow[u0c], g1 = frow[u0c + 1];
    r[i] = valid ? (g0 * (1.f - frac) + g1 * frac) * (float)(M_PI / V_) : 0.f;
  }
  half2v A = { (f16)r[0], (f16)r[1] };
  half2v B = { (f16)r[2], (f16)r[3] };
  #pragma unroll
  for (int k = 2; k <= 256; k <<= 1) {
    #pragma unroll
    for (int j = k >> 1; j > 0; j >>= 1) {
      if (j >= 4) {
        int jl = j >> 2;
        bool low = (lane & jl) == 0;
        bool up = (lane & (k >> 2)) == 0;
        bool keepmin = (low == up);
        int ia = __builtin_bit_cast(int, A);
        int ib = __builtin_bit_cast(int, B);
        half2v Ao = __builtin_bit_cast(half2v, __shfl_xor(ia, jl, 64));
        half2v Bo = __builtin_bit_cast(half2v, __shfl_xor(ib, jl, 64));
        half2v Amn = __builtin_elementwise_min(A, Ao);
        half2v Amx = __builtin_elementwise_max(A, Ao);
        half2v Bmn = __builtin_elementwise_min(B, Bo);
        half2v Bmx = __builtin_elementwise_max(B, Bo);
        A = keepmin ? Amn : Amx;
        B = keepmin ? Bmn : Bmx;
      } else if (j == 2) {
        bool up = (lane & (k >> 2)) == 0;
        half2v mn = __builtin_elementwise_min(A, B);
        half2v mx = __builtin_elementwise_max(A, B);
        A = up ? mn : mx;
        B = up ? mx : mn;
      } else {  // j == 1
        unsigned ua = __builtin_bit_cast(unsigned, A);
        unsigned ub = __builtin_bit_cast(unsigned, B);
        half2v As = __builtin_bit_cast(half2v, (ua >> 16) | (ua << 16));
        half2v Bs = __builtin_bit_cast(half2v, (ub >> 16) | (ub << 16));
        unsigned amn = __builtin_bit_cast(unsigned, __builtin_elementwise_min(A, As));
        unsigned amx = __builtin_bit_cast(unsigned, __builtin_elementwise_max(A, As));
        unsigned bmn = __builtin_bit_cast(unsigned, __builtin_elementwise_min(B, Bs));
        unsigned bmx = __builtin_bit_cast(unsigned, __builtin_elementwise_max(B, Bs));
        unsigned Aasc  = (amn & 0xFFFFu) | (amx & 0xFFFF0000u);
        unsigned Adesc = (amx & 0xFFFFu) | (amn & 0xFFFF0000u);
        unsigned Basc  = (bmn & 0xFFFFu) | (bmx & 0xFFFF0000u);
        unsigned Bdesc = (bmx & 0xFFFFu) | (bmn & 0xFFFF0000u);
        bool upA, upB;
        if (k == 2) { upA = true; upB = false; }
        else { upA = upB = ((lane & (k >> 2)) == 0); }
        A = __builtin_bit_cast(half2v, upA ? Aasc : Adesc);
        B = __builtin_bit_cast(half2v, upB ? Basc : Bdesc);
      }
    }
  }
  half4 o;
  o[0] = A[0]; o[1] = A[1]; o[2] = B[0]; o[3] = B[1];
  *(half4*)(xt + ((size_t)b * (H_ * W_) + pix) * V_ + lane * 4) = o;
}

// ---------------------------------------------------------------------------
// 3) 3x3 conv, 256 sorted-view channels -> 1; fp32 out. grid (HW/4, nb)
__global__ __launch_bounds__(256) void conv_vred_kernel(
    const f16* __restrict__ xt,
    const float* __restrict__ cw,
    const float* __restrict__ cb,
    float* __restrict__ xin) {
  int tid = threadIdx.x;
  int b = blockIdx.y;
  int lane = tid & 63, wv = tid >> 6;
  int pix = blockIdx.x * 4 + wv;
  int h = pix >> 8, w = pix & 255;
  const f16* xtb = xt + (size_t)b * (H_ * W_) * V_;
  float wr[9][4];
  #pragma unroll
  for (int tap = 0; tap < 9; ++tap)
    #pragma unroll
    for (int i = 0; i < 4; ++i)
      wr[tap][i] = cw[(lane * 4 + i) * 9 + tap];
  float acc = 0.f;
  #pragma unroll
  for (int dy = -1; dy <= 1; ++dy) {
    int hh = h + dy;
    if (hh < 0 || hh >= H_) continue;
    #pragma unroll
    for (int dx = -1; dx <= 1; ++dx) {
      int ww = w + dx;
      if (ww < 0 || ww >= W_) continue;
      const f16* base = xtb + (((size_t)hh << 8) + ww) * V_ + lane * 4;
      half4 x4 = *(const half4*)base;
      int tap = (dy + 1) * 3 + dx + 1;
      acc += (float)x4[0] * wr[tap][0] + (float)x4[1] * wr[tap][1] +
             (float)x4[2] * wr[tap][2] + (float)x4[3] * wr[tap][3];
    }
  }
  for (int off = 32; off > 0; off >>= 1) acc += __shfl_down(acc, off);
  if (lane == 0) xin[(size_t)b * (H_ * W_) + pix] = acc + cb[0];
}

// ---------------------------------------------------------------------------
// 4) weight transpose+cast -> wT[layer][tap][cig][co][ci16] f16
__global__ void wtrans_kernel(const float* __restrict__ enc_w,
                              const float* __restrict__ dec_w,
                              f16* __restrict__ wT) {
  int idx = blockIdx.x * 256 + threadIdx.x;
  const int TOT = 8 * 25 * 96 * 96;
  if (idx >= TOT) return;
  int ci16 = idx & 15;
  int t1 = idx >> 4;
  int co = t1 % 96;
  int t2 = t1 / 96;
  int cig = t2 % 6;
  int t3 = t2 / 6;
  int tap = t3 % 25;
  int l = t3 / 25;
  int ci = cig * 16 + ci16;
  const float* src = (l < 4) ? (enc_w + (size_t)l * 96 * 96 * 25)
                             : (dec_w + (size_t)(l - 4) * 96 * 96 * 25);
  wT[idx] = (f16)src[((size_t)co * 96 + ci) * 25 + tap];
}

// ---------------------------------------------------------------------------
// 5) MFMA implicit-GEMM 5x5 conv 96->96, barrier-free, B-window row reuse,
// EXPLICIT software pipeline: 30 fully-unrolled (cig,dx) steps; A-fragments
// double-buffered one step ahead (static slots). Linear LDS (conflict-free).
// grid (128, 1, nb), block 768.
__global__ __launch_bounds__(768, 3) void conv5_mfma_kernel(
    const f16* __restrict__ act,   // [nb][6][H*W][16]
    const f16* __restrict__ wTl,   // [25][6][96][16]
    const float* __restrict__ bias,
    const f16* __restrict__ res,   // nullable, same layout as act
    f16* __restrict__ outp) {
  int tid = threadIdx.x;
  int lane = tid & 63;
  int l31 = lane & 31, lh = lane >> 5;
  int wvi = tid >> 6;       // 0..11
  int c = wvi >> 2;         // co-group 0..2
  int q = wvi & 3;          // row quad 0..3
  int bt = blockIdx.x;
  int x0 = (bt & 7) * 32;
  int y0 = (bt >> 3) * 16;
  size_t bofs = (size_t)blockIdx.z * ((size_t)H_ * W_ * CH_);
  const f16* actb = act + bofs;

  __shared__ __align__(16) f16 tile[6 * 20 * 36 * 16];
  char* tb = (char*)tile;
  const int PLANE = 20 * 36 * 32;   // 23040 B
  const int ROWB  = 36 * 32;        // 1152 B
  const size_t GSTR = (size_t)H_ * W_ * 16;  // group stride (f16)

  // ---- stage whole 96-ci tile once; linear LDS, contiguous writes ----
  #pragma unroll
  for (int g = 0; g < 6; ++g) {
    const f16* gb = actb + (size_t)g * GSTR;
    #pragma unroll
    for (int pass = 0; pass < 2; ++pass) {
      int idx = pass * 768 + tid;          // 1440 slots = 720 cells x 2
      int cell = idx >> 1, j = idx & 1;
      if (cell < 720) {
        int row = cell / 36, xx = cell % 36;
        int gy = y0 + row - 2, gx = x0 + xx - 2;
        bool va = (gy >= 0 && gy < H_ && gx >= 0 && gx < W_);
        uint4 v = {0u, 0u, 0u, 0u};
        if (va) v = *(const uint4*)(gb + ((size_t)(gy * W_ + gx)) * 16 + j * 8);
        *(uint4*)(tb + g * PLANE + idx * 16) = v;
      }
    }
  }
  __syncthreads();

  // ds_read base per dx (linear; plane/row added as constants)
  int dsb[5];
  #pragma unroll
  for (int dx = 0; dx < 5; ++dx)
    dsb[dx] = (l31 + dx) * 32 + lh * 16;

  f32x16 acc[4];
  #pragma unroll
  for (int i = 0; i < 4; ++i)
    #pragma unroll
    for (int r = 0; r < 16; ++r) acc[i][r] = 0.f;

  const f16* wc = wTl + (size_t)(c * 32 + l31) * 16 + lh * 8;
  char* pbq = tb + 4 * q * ROWB;

  half8 Af[2][5];

  // step t = cig*5 + dx, fully static
  #define LOADA(t, s)                                                        \
    {                                                                        \
      const f16* wp_ = wc + (size_t)((t) / 5) * (96 * 16);                   \
      _Pragma("unroll")                                                      \
      for (int dy_ = 0; dy_ < 5; ++dy_)                                      \
        Af[s][dy_] = *(const half8*)(wp_ +                                   \
            (size_t)(dy_ * 5 + ((t) % 5)) * (6 * 96 * 16));                  \
    }
  #define STEP(t)                                                            \
    {                                                                        \
      char* pb_ = pbq + ((t) / 5) * PLANE;                                   \
      half8 Bw[8];                                                           \
      _Pragma("unroll")                                                      \
      for (int k_ = 0; k_ < 8; ++k_)                                         \
        Bw[k_] = *(const half8*)(pb_ + k_ * ROWB + dsb[(t) % 5]);            \
      if ((t) < 29) LOADA((t) + 1, ((t) + 1) & 1);                           \
      _Pragma("unroll")                                                      \
      for (int dy_ = 0; dy_ < 5; ++dy_) {                                    \
        half8 a_ = Af[(t) & 1][dy_];                                         \
        acc[0] = __builtin_amdgcn_mfma_f32_32x32x16_f16(a_, Bw[dy_ + 0], acc[0], 0, 0, 0); \
        acc[1] = __builtin_amdgcn_mfma_f32_32x32x16_f16(a_, Bw[dy_ + 1], acc[1], 0, 0, 0); \
        acc[2] = __builtin_amdgcn_mfma_f32_32x32x16_f16(a_, Bw[dy_ + 2], acc[2], 0, 0, 0); \
        acc[3] = __builtin_amdgcn_mfma_f32_32x32x16_f16(a_, Bw[dy_ + 3], acc[3], 0, 0, 0); \
      }                                                                      \
    }

  LOADA(0, 0);
  STEP(0);  STEP(1);  STEP(2);  STEP(3);  STEP(4);
  STEP(5);  STEP(6);  STEP(7);  STEP(8);  STEP(9);
  STEP(10); STEP(11); STEP(12); STEP(13); STEP(14);
  STEP(15); STEP(16); STEP(17); STEP(18); STEP(19);
  STEP(20); STEP(21); STEP(22); STEP(23); STEP(24);
  STEP(25); STEP(26); STEP(27); STEP(28); STEP(29);
  #undef LOADA
  #undef STEP

  // epilogue: C col = pixel x (lane&31), row co = (reg&3)+8*(reg>>2)+4*lh.
  // Group-planar output: ch = c*32+g*8+lh*4+r -> group c*2+(g>>1), off (g&1)*8+lh*4.
  int x = x0 + l31;
  #pragma unroll
  for (int i = 0; i < 4; ++i) {
    int y = y0 + 4 * q + i;
    int p = y * W_ + x;
    f32x16 a = acc[i];
    #pragma unroll
    for (int g = 0; g < 4; ++g) {
      int cg = c * 2 + (g >> 1);
      size_t ao = bofs + (size_t)cg * GSTR + (size_t)p * 16 + (g & 1) * 8 + lh * 4;
      half4 rv;
      if (res) rv = *(const half4*)(res + ao);
      half4 o4;
      #pragma unroll
      for (int r = 0; r < 4; ++r) {
        float v = a[g * 4 + r] + bias[c * 32 + g * 8 + lh * 4 + r];
        if (res) v += (float)rv[r];
        o4[r] = (f16)fmaxf(v, 0.f);
      }
      *(half4*)(outp + ao) = o4;
    }
  }
}

// ---------------------------------------------------------------------------
// 6) first layer 1->96 direct, group-planar writes. grid (256, nb).
__global__ __launch_bounds__(256) void conv5_first_kernel(
    const float* __restrict__ xin, const float* __restrict__ w0,
    const float* __restrict__ bias, f16* __restrict__ A) {
  int tid = threadIdx.x;
  int tx = tid & 15, ty = tid >> 4;
  int x0 = (blockIdx.x & 15) * 16, y0 = (blockIdx.x >> 4) * 16;
  const float* xb = xin + (size_t)blockIdx.y * (H_ * W_);
  __shared__ float t[20][20];
  __shared__ float ws[CH_ * 25];
  for (int i = tid; i < 400; i += 256) {
    int r = i / 20, cc = i % 20;
    int gy = y0 + r - 2, gx = x0 + cc - 2;
    t[r][cc] = (gy >= 0 && gy < H_ && gx >= 0 && gx < W_) ? xb[gy * W_ + gx] : 0.f;
  }
  for (int i = tid; i < CH_ * 25; i += 256) ws[i] = w0[i];
  __syncthreads();
  float xv[25];
  #pragma unroll
  for (int k = 0; k < 25; ++k) xv[k] = t[ty + k / 5][tx + k % 5];
  size_t base = (size_t)blockIdx.y * ((size_t)H_ * W_ * CH_);
  const size_t GSTR = (size_t)H_ * W_ * 16;
  int p = (y0 + ty) * W_ + x0 + tx;
  #pragma unroll
  for (int g = 0; g < 6; ++g) {
    f16 tmp[16];
    #pragma unroll
    for (int cc = 0; cc < 16; ++cc) {
      int ch = g * 16 + cc;
      float a0 = bias[ch];
      #pragma unroll
      for (int k = 0; k < 25; ++k) a0 = fmaf(xv[k], ws[ch * 25 + k], a0);
      tmp[cc] = (f16)fmaxf(a0, 0.f);
    }
    f16* Ap = A + base + g * GSTR + (size_t)p * 16;
    *(uint4*)(Ap) = *(uint4*)(tmp);
    *(uint4*)(Ap + 8) = *(uint4*)(tmp + 8);
  }
}

// ---------------------------------------------------------------------------
// 7) last layer 96->1 + x_in residual, relu, fp32 out. Group-planar input,
// 6 LDS planes [400][16] XOR-swizzled, b128 reads, fdot2. grid (256, nb).
__global__ __launch_bounds__(256) void conv5_last_kernel(
    const f16* __restrict__ A, const float* __restrict__ wN,
    const float* __restrict__ bias, const float* __restrict__ xin,
    float* __restrict__ outp) {
  int tid = threadIdx.x;
  int tx = tid & 15, ty = tid >> 4;
  int x0 = (blockIdx.x & 15) * 16, y0 = (blockIdx.x >> 4) * 16;
  size_t bo = (size_t)blockIdx.y * (H_ * W_);
  const f16* Ab = A + bo * CH_;
  const size_t GSTR = (size_t)H_ * W_ * 16;
  __shared__ __align__(16) f16 t[6 * 400 * 16];   // 76800 B
  __shared__ __align__(16) f16 wh[25 * CH_];      // 4800 B, [k][ch]
  char* tb = (char*)t;
  const int LPLANE = 400 * 32;                    // 12800 B
  for (int i = tid; i < 25 * CH_; i += 256) {
    int k = i / CH_, ci = i % CH_;
    wh[i] = (f16)wN[ci * 25 + k];
  }
  #pragma unroll
  for (int g = 0; g < 6; ++g) {
    const f16* Ag = Ab + (size_t)g * GSTR;
    for (int idx = tid; idx < 800; idx += 256) {
      int cell = idx >> 1, j = idx & 1;
      int r = cell / 20, cc = cell % 20;
      int gy = y0 + r - 2, gx = x0 + cc - 2;
      bool va = (gy >= 0 && gy < H_ && gx >= 0 && gx < W_);
      uint4 v = {0u, 0u, 0u, 0u};
      if (va) v = *(const uint4*)(Ag + ((size_t)(gy * W_ + gx)) * 16 + j * 8);
      int sw = (cell & 7) << 4;
      *(uint4*)(tb + g * LPLANE + ((cell * 32 + j * 16) ^ sw)) = v;
    }
  }
  __syncthreads();
  float acc = bias[0];
  #pragma unroll
  for (int k = 0; k < 25; ++k) {
    int cellr = (ty + k / 5) * 20 + tx + k % 5;
    int sw = (cellr & 7) << 4;
    #pragma unroll
    for (int g = 0; g < 6; ++g) {
      const half2v* wp = (const half2v*)(wh + k * CH_ + g * 16);
      uint4 a0 = *(const uint4*)(tb + g * LPLANE + ((cellr * 32) ^ sw));
      uint4 a1 = *(const uint4*)(tb + g * LPLANE + ((cellr * 32 + 16) ^ sw));
      acc = FDOT2(__builtin_bit_cast(half2v, a0.x), wp[0], acc);
      acc = FDOT2(__builtin_bit_cast(half2v, a0.y), wp[1], acc);
      acc = FDOT2(__builtin_bit_cast(half2v, a0.z), wp[2], acc);
      acc = FDOT2(__builtin_bit_cast(half2v, a0.w), wp[3], acc);
      acc = FDOT2(__builtin_bit_cast(half2v, a1.x), wp[4], acc);
      acc = FDOT2(__builtin_bit_cast(half2v, a1.y), wp[5], acc);
      acc = FDOT2(__builtin_bit_cast(half2v, a1.z), wp[6], acc);
      acc = FDOT2(__builtin_bit_cast(half2v, a1.w), wp[7], acc);
    }
  }
  int pix = (y0 + ty) * W_ + x0 + tx;
  acc += xin[bo + pix];
  outp[bo + pix] = fmaxf(acc, 0.f);
}

// ---------------------------------------------------------------------------
__global__ void diag_kernel(float* __restrict__ out, int code, int wsMiB) {
  out[0] = (float)(code * 1000000 + wsMiB);
}

// ---------------------------------------------------------------------------
extern "C" void kernel_launch(void* const* d_in, const int* in_sizes, int n_in,
                              void* d_out, int out_size, void* d_ws, size_t ws_size,
                              hipStream_t stream) {
  const float* p       = (const float*)d_in[0];
  const float* pweight = (const float*)d_in[1];
  const float* ramp    = (const float*)d_in[2];
  const float* views   = (const float*)d_in[3];
  const float* conv_w  = (const float*)d_in[4];
  const float* conv_b  = (const float*)d_in[5];
  const float* enc_w0  = (const float*)d_in[6];
  const float* enc_w   = (const float*)d_in[7];
  const float* enc_b   = (const float*)d_in[8];
  const float* dec_w   = (const float*)d_in[9];
  const float* dec_wN  = (const float*)d_in[10];
  const float* dec_b   = (const float*)d_in[11];
  const float* dec_bN  = (const float*)d_in[12];
  float* out           = (float*)d_out;   // [2][256][256] fp32

  char* wsb   = (char*)d_ws;
  float* filt = (float*)(wsb);
  float* xin  = (float*)(wsb + 0x100000u);
  f16* wT     = (f16*)(wsb + 0x180000u);
  const size_t AOFF = 0x508000u;
  f16* xt     = (f16*)(wsb + AOFF);

  const size_t ACT = (size_t)H_ * W_ * CH_;
  const size_t NEEDED_SEQ  = AOFF + 3 * ACT * 2;
  const size_t NEEDED_DUAL = AOFF + 6 * ACT * 2;
  int wsMiB = (int)(ws_size >> 20);
  if (ws_size < NEEDED_SEQ) {
    diag_kernel<<<1, 1, 0, stream>>>(out, 9, wsMiB);
    return;
  }
  int nb = (ws_size >= NEEDED_DUAL) ? 2 : 1;
  size_t bufSz = (size_t)nb * ACT;
  f16* A  = (f16*)(wsb + AOFF);
  f16* Bb = A + bufSz;
  f16* C  = Bb + bufSz;

  const int HW = H_ * W_;
  const size_t WTL = 25 * 96 * 96;

  filter_kernel<<<dim3(V_, B_), 256, 0, stream>>>(p, pweight, ramp, filt);
  wtrans_kernel<<<7200, 256, 0, stream>>>(enc_w, dec_w, wT);

  if (nb == 2) {
    backproj_sort_kernel<<<dim3(HW / 4, 2), 256, 0, stream>>>(filt, views, xt);
    conv_vred_kernel<<<dim3(HW / 4, 2), 256, 0, stream>>>(xt, conv_w, conv_b, xin);
  } else {
    for (int b = 0; b < B_; ++b) {
      backproj_sort_kernel<<<dim3(HW / 4, 1), 256, 0, stream>>>(filt + (size_t)b * V_ * D_, views, xt);
      conv_vred_kernel<<<dim3(HW / 4, 1), 256, 0, stream>>>(xt, conv_w, conv_b, xin + (size_t)b * HW);
    }
  }

  auto run_net = [&](const float* xin_g, float* out_g, int nbat) {
    dim3 gL(128, 1, nbat);
    dim3 gS(256, nbat);
    conv5_first_kernel<<<gS, 256, 0, stream>>>(xin_g, enc_w0, enc_b, A);
    conv5_mfma_kernel<<<gL, 768, 0, stream>>>(A,  wT + 0 * WTL, enc_b + 96,  nullptr, Bb); // h2 (r2)
    conv5_mfma_kernel<<<gL, 768, 0, stream>>>(Bb, wT + 1 * WTL, enc_b + 192, nullptr, A);  // h3
    conv5_mfma_kernel<<<gL, 768, 0, stream>>>(A,  wT + 2 * WTL, enc_b + 288, nullptr, C);  // h4 (r3)
    conv5_mfma_kernel<<<gL, 768, 0, stream>>>(C,  wT + 3 * WTL, enc_b + 384, nullptr, A);  // h5
    conv5_mfma_kernel<<<gL, 768, 0, stream>>>(A,  wT + 4 * WTL, dec_b + 0,   C,       C);  // h6 (+r3)
    conv5_mfma_kernel<<<gL, 768, 0, stream>>>(C,  wT + 5 * WTL, dec_b + 96,  nullptr, A);  // h7
    conv5_mfma_kernel<<<gL, 768, 0, stream>>>(A,  wT + 6 * WTL, dec_b + 192, Bb,      Bb); // h8 (+r2)
    conv5_mfma_kernel<<<gL, 768, 0, stream>>>(Bb, wT + 7 * WTL, dec_b + 288, nullptr, A);  // h9
    conv5_last_kernel<<<gS, 256, 0, stream>>>(A, dec_wN, dec_bN, xin_g, out_g);
  };

  if (nb == 2) {
    run_net(xin, out, 2);
  } else {
    for (int b = 0; b < B_; ++b)
      run_net(xin + (size_t)b * HW, out + (size_t)b * HW, 1);
  }
}